// Round 9
// baseline (390.510 us; speedup 1.0000x reference)
//
#include <hip/hip_runtime.h>
#include <hip/hip_bf16.h>

#define NDIM 2048
#define BS   64
#define NM4  (NDIM * NDIM / 4)
#define BSN  ((size_t)BS * NDIM)
#define SMEM_HEAVY 98304   // wgemm: 6 x 16 KB pipeline buffers (skinny fits inside)
#define SMEM_LIGHT 69632   // skinny: 64 KB panel + 4 KB reduction

typedef __bf16 bf16_t;
typedef __bf16 bf16x4 __attribute__((ext_vector_type(4)));
typedef __bf16 bf16x8 __attribute__((ext_vector_type(8)));
typedef float  f32x4  __attribute__((ext_vector_type(4)));

// Async global->LDS, 16 B per lane.  LDS dest = wave-uniform base + lane*16.
__device__ __forceinline__ void gload16(const void* g, void* lds) {
  __builtin_amdgcn_global_load_lds(
      (const __attribute__((address_space(1))) void*)g,
      (__attribute__((address_space(3))) void*)lds, 16, 0, 0);
}
// 32-bit LDS byte offset of a generic pointer into __shared__.
__device__ __forceinline__ uint32_t lds_off(void* p) {
  return (uint32_t)(uintptr_t)(__attribute__((address_space(3))) void*)p;
}

#define WBN(n) asm volatile("s_waitcnt vmcnt(" #n ")\n\ts_barrier" ::: "memory")

// ---------------------------------------------------------------------------
// prep (512 thr, 3072 blocks): b<1024 convert H,U (+y, traj0); else 64x64
// fp32->bf16 vectorized transposes of Dinv, invM.
// ---------------------------------------------------------------------------
__global__ __launch_bounds__(512) void prep(
    const float* __restrict__ H, const float* __restrict__ U,
    const float* __restrict__ Dinv, const float* __restrict__ invM,
    const float* __restrict__ y,
    bf16_t* __restrict__ H16, bf16_t* __restrict__ U16,
    bf16_t* __restrict__ Dt, bf16_t* __restrict__ iMt,
    bf16_t* __restrict__ y16, float* __restrict__ traj0) {
  __shared__ bf16_t tile[64][72];
  int b = blockIdx.x, tid = threadIdx.x;
  if (b < 1024) {
#pragma unroll
    for (int i = 0; i < 4; ++i) {
      int idx = b * 2048 + i * 512 + tid;
      const float* src = (idx < NM4) ? H : U;
      bf16_t* dst = (idx < NM4) ? H16 : U16;
      int j = (idx < NM4) ? idx : idx - NM4;
      float4 v = ((const float4*)src)[j];
      bf16x4 o = {(bf16_t)v.x, (bf16_t)v.y, (bf16_t)v.z, (bf16_t)v.w};
      ((bf16x4*)dst)[j] = o;
    }
    int yi = b * 512 + tid;
    if (yi < BS * NDIM / 4) {
      float4 w = ((const float4*)y)[yi];
      bf16x4 o2 = {(bf16_t)w.x, (bf16_t)w.y, (bf16_t)w.z, (bf16_t)w.w};
      ((bf16x4*)y16)[yi] = o2;
      ((float4*)traj0)[yi] = make_float4(0.f, 0.f, 0.f, 0.f);
    }
  } else {
    int id = b - 1024;
    const float* src = (id < 1024) ? Dinv : invM;
    bf16_t* dst = (id < 1024) ? Dt : iMt;
    id &= 1023;
    int bx = id & 31, by = id >> 5;
    int r = tid >> 3, c8 = (tid & 7) * 8;
    const float* sp = src + (size_t)(by * 64 + r) * NDIM + bx * 64 + c8;
    float4 v0 = *(const float4*)sp;
    float4 v1 = *(const float4*)(sp + 4);
    bf16_t* t = &tile[r][c8];
    t[0] = (bf16_t)v0.x; t[1] = (bf16_t)v0.y; t[2] = (bf16_t)v0.z; t[3] = (bf16_t)v0.w;
    t[4] = (bf16_t)v1.x; t[5] = (bf16_t)v1.y; t[6] = (bf16_t)v1.z; t[7] = (bf16_t)v1.w;
    __syncthreads();
    bf16x8 o;
#pragma unroll
    for (int j = 0; j < 8; ++j) o[j] = tile[c8 + j][r];
    *(bf16x8*)(dst + (size_t)(bx * 64 + r) * NDIM + by * 64 + c8) = o;
  }
}

// ---------------------------------------------------------------------------
// wgemm v5: 2048^3 NT GEMM, 512 thr, 128x128 tile, BK=32, 64 chunks,
// 6-buffer / 5-stage-deep async pipeline (vmcnt(8) => oldest stage complete;
// ~1250 cyc of prefetch lead > 900 cyc HBM first-touch latency).
// XCD-aware 4x4 tile-block swizzle (b%8 = XCD): 4 A-panels + 4 B-panels
// = 4 MB per XCD, fits its private L2, so re-reads are ~200 cyc not 600-900.
// Fragment loads are raw asm ds_read_b128; readiness via lgkmcnt(0) that
// redefines the fragment regs.  1 block/CU (96 KB LDS).
// ---------------------------------------------------------------------------
__device__ __forceinline__ void wgemm_role(
    const bf16_t* __restrict__ A, const bf16_t* __restrict__ Bt,
    bf16_t* __restrict__ C, bf16_t* __restrict__ Ct, int blk, char* smem) {
  int tid = threadIdx.x, lane = tid & 63, wave = tid >> 6;
  // XCD swizzle: XCD x gets tile-blocks t = 2x, 2x+1; each 4x4 tiles.
  int x = blk & 7, j = blk >> 3;
  int t = x * 2 + (j >> 4);
  int mi = (j >> 2) & 3, ni = j & 3;
  int m0 = ((t >> 2) * 4 + mi) * 128;
  int n0 = ((t & 3) * 4 + ni) * 128;

  int rl = lane & 15, q = lane >> 4;
  const bf16_t* Ag = A  + (size_t)(m0 + wave * 16 + rl) * NDIM + q * 8;
  const bf16_t* Bg = Bt + (size_t)(n0 + wave * 16 + rl) * NDIM + q * 8;
  char* ldsA = smem + wave * 1024;          // per-wave staging slice, + buf*16384
  char* ldsB = smem + 8192 + wave * 1024;

  int wr2 = (wave & 3) * 2, wc4 = (wave >> 2) * 4;
  uint32_t abase = lds_off(smem) + wr2 * 1024 + lane * 16;
  uint32_t bbase = lds_off(smem) + 8192 + wc4 * 1024 + lane * 16;

  f32x4 acc[2][4];
#pragma unroll
  for (int i = 0; i < 2; ++i)
#pragma unroll
    for (int jj = 0; jj < 4; ++jj) acc[i][jj] = (f32x4){0.f, 0.f, 0.f, 0.f};

#define STAGE(buf, s)                             \
  {                                               \
    int _k = (s) * 32;                            \
    gload16(Ag + _k, ldsA + (buf) * 16384);       \
    gload16(Bg + _k, ldsB + (buf) * 16384);       \
  }
#define COMPUTE(bb)                                                            \
  {                                                                            \
    uint32_t av = abase + (bb) * 16384;                                        \
    uint32_t bv = bbase + (bb) * 16384;                                        \
    bf16x8 af0, af1, bg0, bg1, bg2, bg3;                                       \
    asm volatile("ds_read_b128 %0, %1"             : "=v"(af0) : "v"(av));     \
    asm volatile("ds_read_b128 %0, %1 offset:1024" : "=v"(af1) : "v"(av));     \
    asm volatile("ds_read_b128 %0, %1"             : "=v"(bg0) : "v"(bv));     \
    asm volatile("ds_read_b128 %0, %1 offset:1024" : "=v"(bg1) : "v"(bv));     \
    asm volatile("ds_read_b128 %0, %1 offset:2048" : "=v"(bg2) : "v"(bv));     \
    asm volatile("ds_read_b128 %0, %1 offset:3072" : "=v"(bg3) : "v"(bv));     \
    asm volatile("s_waitcnt lgkmcnt(0)"                                        \
                 : "+v"(af0), "+v"(af1), "+v"(bg0), "+v"(bg1), "+v"(bg2),      \
                   "+v"(bg3));                                                 \
    acc[0][0] = __builtin_amdgcn_mfma_f32_16x16x32_bf16(af0, bg0, acc[0][0], 0, 0, 0); \
    acc[0][1] = __builtin_amdgcn_mfma_f32_16x16x32_bf16(af0, bg1, acc[0][1], 0, 0, 0); \
    acc[0][2] = __builtin_amdgcn_mfma_f32_16x16x32_bf16(af0, bg2, acc[0][2], 0, 0, 0); \
    acc[0][3] = __builtin_amdgcn_mfma_f32_16x16x32_bf16(af0, bg3, acc[0][3], 0, 0, 0); \
    acc[1][0] = __builtin_amdgcn_mfma_f32_16x16x32_bf16(af1, bg0, acc[1][0], 0, 0, 0); \
    acc[1][1] = __builtin_amdgcn_mfma_f32_16x16x32_bf16(af1, bg1, acc[1][1], 0, 0, 0); \
    acc[1][2] = __builtin_amdgcn_mfma_f32_16x16x32_bf16(af1, bg2, acc[1][2], 0, 0, 0); \
    acc[1][3] = __builtin_amdgcn_mfma_f32_16x16x32_bf16(af1, bg3, acc[1][3], 0, 0, 0); \
  }

  // prologue: 5 stages in flight
  STAGE(0, 0); STAGE(1, 1); STAGE(2, 2); STAGE(3, 3); STAGE(4, 4);
#pragma unroll 1
  for (int g = 0; g < 9; ++g) {        // chunks 6g .. 6g+5 (0..53)
    int i = g * 6;
    WBN(8); STAGE(5, i + 5);  COMPUTE(0);
    WBN(8); STAGE(0, i + 6);  COMPUTE(1);
    WBN(8); STAGE(1, i + 7);  COMPUTE(2);
    WBN(8); STAGE(2, i + 8);  COMPUTE(3);
    WBN(8); STAGE(3, i + 9);  COMPUTE(4);
    WBN(8); STAGE(4, i + 10); COMPUTE(5);
  }
  WBN(8); STAGE(5, 59); COMPUTE(0);    // chunk 54
  WBN(8); STAGE(0, 60); COMPUTE(1);    // 55
  WBN(8); STAGE(1, 61); COMPUTE(2);    // 56
  WBN(8); STAGE(2, 62); COMPUTE(3);    // 57
  WBN(8); STAGE(3, 63); COMPUTE(4);    // 58
  WBN(8); COMPUTE(5);                  // 59
  WBN(6); COMPUTE(0);                  // 60 (buffer 0 = stage 60)
  WBN(4); COMPUTE(1);                  // 61
  WBN(2); COMPUTE(2);                  // 62
  WBN(0); COMPUTE(3);                  // 63
#undef STAGE
#undef COMPUTE

  // normal-orientation store (C[m][n])
#pragma unroll
  for (int i = 0; i < 2; ++i)
#pragma unroll
    for (int jj = 0; jj < 4; ++jj)
#pragma unroll
      for (int r = 0; r < 4; ++r)
        C[(size_t)(m0 + (wr2 + i) * 16 + q * 4 + r) * NDIM + n0 + (wc4 + jj) * 16 + rl] =
            (bf16_t)acc[i][jj][r];

  // optional transposed store (Ct[n][m]) via LDS round-trip
  if (Ct) {
    __syncthreads();
    bf16_t (*tileT)[136] = (bf16_t(*)[136])smem;   // 128 x 136 x 2 B = 34.8 KB
#pragma unroll
    for (int i = 0; i < 2; ++i)
#pragma unroll
      for (int jj = 0; jj < 4; ++jj)
#pragma unroll
        for (int r = 0; r < 4; ++r)
          tileT[(wc4 + jj) * 16 + rl][(wr2 + i) * 16 + q * 4 + r] = (bf16_t)acc[i][jj][r];
    __syncthreads();
#pragma unroll
    for (int tt = 0; tt < 4; ++tt) {
      int v = tt * 512 + tid, row = v >> 4, c8 = (v & 15) * 8;
      *(bf16x8*)(Ct + (size_t)(n0 + row) * NDIM + m0 + c8) = *(bf16x8*)&tileT[row][c8];
    }
  }
}

// ---------------------------------------------------------------------------
// skinny v3: C[64,16] = add + sign*(A[64,2048] @ Bt^T cols n0..+15).
// Panel (64 KB, fragment order) staged async; waves 0-3 K-half0 / 4-7 K-half1;
// 8 round-robin accumulators; LDS f32 reduction joins halves.
// ---------------------------------------------------------------------------
__device__ __forceinline__ void skinny_role(
    const bf16_t* __restrict__ A, const bf16_t* __restrict__ Bt, int n0, char* smem,
    const float* __restrict__ add, float sign,
    float* o32, float* o32b, bf16_t* o16) {
  int tid = threadIdx.x, lane = tid & 63, wave = tid >> 6;
  int rl = lane & 15, q = lane >> 4;
#pragma unroll
  for (int i = 0; i < 8; ++i) {
    const bf16_t* g = Bt + (size_t)(n0 + rl) * NDIM + (i * 8 + wave) * 32 + q * 8;
    gload16(g, smem + (size_t)(i * 512 + wave * 64) * 16);
  }
  __syncthreads();

  int ms = (wave & 3) * 16, kh = wave >> 2;
  const bf16x8* Ap = (const bf16x8*)(A + (size_t)(ms + rl) * NDIM) + q + kh * 128;
  const bf16x8* Bp = (const bf16x8*)smem + lane + kh * 2048;

  f32x4 acc[8];
#pragma unroll
  for (int i = 0; i < 8; ++i) acc[i] = (f32x4){0.f, 0.f, 0.f, 0.f};
#pragma unroll
  for (int c = 0; c < 32; ++c)
    acc[c & 7] = __builtin_amdgcn_mfma_f32_16x16x32_bf16(Ap[c * 4], Bp[c * 64], acc[c & 7], 0, 0, 0);
  f32x4 s = ((acc[0] + acc[1]) + (acc[2] + acc[3])) + ((acc[4] + acc[5]) + (acc[6] + acc[7]));

  f32x4* red = (f32x4*)(smem + 65536);
  if (wave >= 4) red[(wave & 3) * 64 + lane] = s;
  __syncthreads();
  if (wave < 4) {
    s += red[wave * 64 + lane];
    int mrow = ms + q * 4, col = n0 + rl;
#pragma unroll
    for (int r = 0; r < 4; ++r) {
      size_t o = (size_t)(mrow + r) * NDIM + col;
      float v = sign * s[r];
      if (add) v += add[o];
      if (o32)  o32[o]  = v;
      if (o32b) o32b[o] = v;
      if (o16)  o16[o]  = (bf16_t)v;
    }
  }
}

// --------------------------- mega nodes (512 thr) --------------------------
// A: W = U@invM, dual store Wrm+Wt (256 wgemm) || yMF = y@H^T (128 skinny)
__global__ __launch_bounds__(512, 2) void megaA(
    const bf16_t* __restrict__ U16, const bf16_t* __restrict__ iMt16,
    const bf16_t* __restrict__ y16, const bf16_t* __restrict__ H16,
    bf16_t* __restrict__ Wrm, bf16_t* __restrict__ Wt, bf16_t* __restrict__ yMF16) {
  __shared__ char smem[SMEM_HEAVY];
  int b = blockIdx.x;
  if (b < 256) wgemm_role(U16, iMt16, Wrm, Wt, b, smem);
  else         skinny_role(y16, H16, (b - 256) * 16, smem, nullptr, 1.f, nullptr, nullptr, yMF16);
}

// B (light): c = yMF@invM (128) || x0 = yMF@Dinv (128 -> z0)
__global__ __launch_bounds__(512, 4) void megaB(
    const bf16_t* __restrict__ yMF16, const bf16_t* __restrict__ iMt16,
    const bf16_t* __restrict__ Dt16,
    float* __restrict__ c32, bf16_t* __restrict__ c16, bf16_t* __restrict__ z0) {
  __shared__ char smem[SMEM_LIGHT];
  int b = blockIdx.x;
  if (b < 128) skinny_role(yMF16, iMt16, b * 16, smem, nullptr, 1.f, c32, nullptr, c16);
  else         skinny_role(yMF16, Dt16, (b - 128) * 16, smem, nullptr, 1.f, nullptr, nullptr, z0);
}

// C: W2 = NT(Wt,Wrm), dual store W2t+W2rm (256) || x1 (128 -> traj[1], z0+BSN)
//    || c2 (128)
__global__ __launch_bounds__(512, 2) void megaC(
    const bf16_t* __restrict__ Wt, const bf16_t* __restrict__ Wrm,
    const bf16_t* __restrict__ z0, const bf16_t* __restrict__ c16,
    const float* __restrict__ c32,
    bf16_t* __restrict__ W2t, bf16_t* __restrict__ W2rm,
    float* __restrict__ traj1, bf16_t* __restrict__ z0b,
    float* __restrict__ c2_32, bf16_t* __restrict__ c2_16) {
  __shared__ char smem[SMEM_HEAVY];
  int b = blockIdx.x;
  if (b < 256)      wgemm_role(Wt, Wrm, W2t, W2rm, b, smem);
  else if (b < 384) skinny_role(z0, Wt, (b - 256) * 16, smem, c32, -1.f, traj1, nullptr, z0b);
  else              skinny_role(c16, Wt, (b - 384) * 16, smem, c32, -1.f, c2_32, nullptr, c2_16);
}

// D (light): x2 (128 -> traj[2], zA0) || x3 (128 -> traj[3], zA1) || c4 (128)
__global__ __launch_bounds__(512, 4) void megaD(
    const bf16_t* __restrict__ W2t, const bf16_t* __restrict__ z0,
    const bf16_t* __restrict__ c2_16, const float* __restrict__ c2_32,
    float* __restrict__ traj2, float* __restrict__ traj3,
    bf16_t* __restrict__ zA, float* __restrict__ c4_32) {
  __shared__ char smem[SMEM_LIGHT];
  int b = blockIdx.x;
  if (b < 128)      skinny_role(z0, W2t, b * 16, smem, c2_32, 1.f, traj2, nullptr, zA);
  else if (b < 256) skinny_role(z0 + BSN, W2t, (b - 128) * 16, smem, c2_32, 1.f, traj3, nullptr, zA + BSN);
  else              skinny_role(c2_16, W2t, (b - 256) * 16, smem, c2_32, 1.f, c4_32, nullptr, nullptr);
}

// E: W4t = NT(W2t,W2rm) (256) || x4 (128 -> traj[4], zA2) || x5 (128 -> traj[5], zA3)
__global__ __launch_bounds__(512, 2) void megaE(
    const bf16_t* __restrict__ W2t, const bf16_t* __restrict__ W2rm,
    const bf16_t* __restrict__ zA_in, const float* __restrict__ c2_32,
    bf16_t* __restrict__ W4t, float* __restrict__ traj4, float* __restrict__ traj5,
    bf16_t* __restrict__ zA) {
  __shared__ char smem[SMEM_HEAVY];
  int b = blockIdx.x;
  if (b < 256)      wgemm_role(W2t, W2rm, W4t, nullptr, b, smem);
  else if (b < 384) skinny_role(zA_in, W2t, (b - 256) * 16, smem, c2_32, 1.f, traj4, nullptr, zA + 2 * BSN);
  else              skinny_role(zA_in + BSN, W2t, (b - 384) * 16, smem, c2_32, 1.f, traj5, nullptr, zA + 3 * BSN);
}

// Quad step: 4 chains x_{k+4} = c4 + x_k@W4.  512 blocks: chain b&3, panel b>>2.
__global__ __launch_bounds__(512, 4) void quad_step(
    const bf16_t* __restrict__ zin, const bf16_t* __restrict__ W4t,
    const float* __restrict__ c4_32, float* __restrict__ trajb,
    bf16_t* __restrict__ zout, float* __restrict__ sfin) {
  __shared__ char smem[SMEM_LIGHT];
  int b = blockIdx.x, ci = b & 3, p = b >> 2;
  skinny_role(zin + (size_t)ci * BSN, W4t, p * 16, smem, c4_32, 1.f,
              trajb + (size_t)ci * BSN, (ci == 3) ? sfin : nullptr,
              zout + (size_t)ci * BSN);
}

// ---------------------------------------------------------------------------
// Host driver: 11 graph nodes.
// ---------------------------------------------------------------------------
extern "C" void kernel_launch(void* const* d_in, const int* in_sizes, int n_in,
                              void* d_out, int out_size, void* d_ws, size_t ws_size,
                              hipStream_t stream) {
  const float* y    = (const float*)d_in[2];
  const float* H    = (const float*)d_in[3];
  const float* Dinv = (const float*)d_in[4];
  const float* U    = (const float*)d_in[5];
  const float* invM = (const float*)d_in[6];

  float* out     = (float*)d_out;
  float* s_final = out;
  float* traj    = out + BSN;

  char* ws = (char*)d_ws;
  size_t off = 0;
  auto alloc = [&](size_t bytes) -> void* {
    void* p = ws + off;
    off += (bytes + 255) & ~(size_t)255;
    return p;
  };
  bf16_t* U16   = (bf16_t*)alloc((size_t)NDIM * NDIM * 2);  // -> W2rm after megaA
  bf16_t* Dt16  = (bf16_t*)alloc((size_t)NDIM * NDIM * 2);  // -> W4t after megaB
  bf16_t* iMt16 = (bf16_t*)alloc((size_t)NDIM * NDIM * 2);
  bf16_t* H16   = (bf16_t*)alloc((size_t)NDIM * NDIM * 2);  // -> W2t after megaA
  bf16_t* Wrm   = (bf16_t*)alloc((size_t)NDIM * NDIM * 2);
  bf16_t* Wt    = (bf16_t*)alloc((size_t)NDIM * NDIM * 2);
  bf16_t* y16   = (bf16_t*)alloc(BSN * 2);
  bf16_t* yMF16 = (bf16_t*)alloc(BSN * 2);
  bf16_t* c16   = (bf16_t*)alloc(BSN * 2);
  bf16_t* c2_16 = (bf16_t*)alloc(BSN * 2);
  float*  c32   = (float*)alloc(BSN * 4);
  float*  c2_32 = (float*)alloc(BSN * 4);
  float*  c4_32 = (float*)alloc(BSN * 4);
  bf16_t* z0    = (bf16_t*)alloc(2 * BSN * 2);  // x0, x1
  bf16_t* zA    = (bf16_t*)alloc(4 * BSN * 2);  // chains x2..x5
  bf16_t* zB    = (bf16_t*)alloc(4 * BSN * 2);
  bf16_t* W2t   = H16;   // H16 dead after megaA
  bf16_t* W2rm  = U16;   // U16 dead after megaA
  bf16_t* W4t   = Dt16;  // Dt16 dead after megaB

  prep<<<3072, 512, 0, stream>>>(H, U, Dinv, invM, y, H16, U16, Dt16, iMt16, y16, traj);
  megaA<<<384, 512, 0, stream>>>(U16, iMt16, y16, H16, Wrm, Wt, yMF16);
  megaB<<<256, 512, 0, stream>>>(yMF16, iMt16, Dt16, c32, c16, z0);
  megaC<<<512, 512, 0, stream>>>(Wt, Wrm, z0, c16, c32, W2t, W2rm,
                                 traj + BSN, z0 + BSN, c2_32, c2_16);
  megaD<<<384, 512, 0, stream>>>(W2t, z0, c2_16, c2_32, traj + 2 * BSN, traj + 3 * BSN,
                                 zA, c4_32);
  megaE<<<512, 512, 0, stream>>>(W2t, W2rm, zA, c2_32, W4t, traj + 4 * BSN, traj + 5 * BSN, zA);

  bf16_t* zcur = zA;
  bf16_t* znxt = zB;
  for (int g = 0; g < 5; ++g) {
    float* sfin = (g == 4) ? s_final : nullptr;
    quad_step<<<512, 512, 0, stream>>>(zcur, W4t, c4_32, traj + (size_t)(6 + 4 * g) * BSN,
                                       znxt, sfin);
    bf16_t* tmp = zcur; zcur = znxt; znxt = tmp;
  }
}